// Round 19
// baseline (7885.585 us; speedup 1.0000x reference)
//
#include <hip/hip_runtime.h>

#define T_LEN 1024
#define B_N   64
#define D_N   256
#define Q_N   128
#define WCOLS 2560      // weights: 256 pu | 256 pv | 1024 gi | 1024 gh
#define GROW  1280      // G row: 1024 gates | 256 md  (partials in Gp region)
#define NT    256
#define NGRP  16        // 16 groups x 4 batches -> 256 WGs, full chip
#define GB    4
#define GWGS  16
#define VP    260       // vsh f32 row pitch
#define VPS   264       // bf16 plane row pitch (shorts)

typedef __attribute__((ext_vector_type(8))) short short8;
typedef __attribute__((ext_vector_type(4))) float floatx4;

#define MFMA16(A, B, C) __builtin_amdgcn_mfma_f32_16x16x32_bf16((A), (B), (C), 0, 0, 0)

__device__ __forceinline__ float fsigmoid(float x) { return 1.f / (1.f + __expf(-x)); }
__device__ __forceinline__ float ftanh(float x) {
  float ax = fabsf(x);
  float e = __expf(-2.f * ax);
  float r = (1.f - e) / (1.f + e);
  return (x < 0.f) ? -r : r;
}

// ---- PROVEN exchange primitives -------------------------------------------
__device__ __forceinline__ floatx4 ld4_sc(const float* a) {
  floatx4 r;
  asm volatile("global_load_dwordx4 %0, %1, off sc0 sc1" : "=v"(r) : "v"(a) : "memory");
  return r;
}
__device__ __forceinline__ float ld1_sc(const float* a) {
  float r;
  asm volatile("global_load_dword %0, %1, off sc0 sc1" : "=v"(r) : "v"(a) : "memory");
  return r;
}
__device__ __forceinline__ void st1_sc(float* a, float v) {
  asm volatile("global_store_dword %0, %1, off sc0 sc1" :: "v"(a), "v"(v) : "memory");
}
__device__ __forceinline__ void vm_drain() { asm volatile("s_waitcnt vmcnt(0)" ::: "memory"); }
#define TIE(x) asm volatile("" : "+v"(x))

// 3-term truncation split of A (p staging only; v is pre-split in LDS)
struct Split3 { short8 h, m, l; };
__device__ __forceinline__ Split3 split8(const float* x) {
  union U { unsigned u[4]; short8 s; } H, M, L;
#pragma unroll
  for (int i = 0; i < 4; ++i) {
    float x0 = x[2 * i], x1 = x[2 * i + 1];
    unsigned h0 = __float_as_uint(x0) & 0xffff0000u;
    unsigned h1 = __float_as_uint(x1) & 0xffff0000u;
    float r0 = x0 - __uint_as_float(h0);
    float r1 = x1 - __uint_as_float(h1);
    unsigned m0 = __float_as_uint(r0) & 0xffff0000u;
    unsigned m1 = __float_as_uint(r1) & 0xffff0000u;
    float s0 = r0 - __uint_as_float(m0);
    float s1 = r1 - __uint_as_float(m1);
    H.u[i] = (h0 >> 16) | h1;
    M.u[i] = (m0 >> 16) | m1;
    L.u[i] = (__float_as_uint(s0) >> 16) | (__float_as_uint(s1) & 0xffff0000u);
  }
  Split3 r; r.h = H.s; r.m = M.s; r.l = L.s; return r;
}

__device__ __forceinline__ floatx4 mfma5(floatx4 acc, const Split3& A, short8 Bh, short8 Bm) {
  acc = MFMA16(A.l, Bh, acc);
  acc = MFMA16(A.m, Bm, acc);
  acc = MFMA16(A.m, Bh, acc);
  acc = MFMA16(A.h, Bm, acc);
  acc = MFMA16(A.h, Bh, acc);
  return acc;
}

// ---------------- prep: W -> bf16 2-way split; WquT; flags=0 -----------------
__global__ void prep_kernel(const float* __restrict__ Wpu, const float* __restrict__ Wqu,
                            const float* __restrict__ Wpv, const float* __restrict__ Wih,
                            const float* __restrict__ Whh,
                            unsigned short* __restrict__ Wh, unsigned short* __restrict__ Wm,
                            float* __restrict__ WquT, unsigned* __restrict__ flags) {
  int idx = blockIdx.x * 256 + threadIdx.x;
  const int total = WCOLS * 256;                // 655360
  if (idx < total) {
    int n = idx >> 8, k = idx & 255;
    float w;
    if      (n < 256)  w = Wpu[k * 256 + n];            // pu
    else if (n < 512)  w = Wpv[k * 256 + (n - 256)];    // pv
    else if (n < 1536) w = Wih[(n - 512) * 256 + k];    // gi
    else               w = Whh[(n - 1536) * 256 + k];   // gh
    unsigned hb = __float_as_uint(w) & 0xffff0000u;
    float r1 = w - __uint_as_float(hb);
    Wh[idx] = (unsigned short)(hb >> 16);
    Wm[idx] = (unsigned short)((__float_as_uint(r1) & 0xffff0000u) >> 16);
  } else if (idx < total + 65536) {
    int i = idx - total, n = i >> 8, k = i & 255;
    WquT[n * 256 + k] = Wqu[k * 256 + n];
  } else if (idx < total + 65536 + 4096) {
    flags[idx - total - 65536] = 0u;
  }
}

// ---------------- prep_qz: qs_b = sum_j q_j ; z_b = Wqu @ qs_b ---------------
__global__ void prep_qz(const float* __restrict__ q, const float* __restrict__ WquT,
                        float* __restrict__ qsout, float* __restrict__ zbout) {
  __shared__ float qsh[256];
  const int b = blockIdx.x, tid = threadIdx.x;
  float s = 0.f;
  for (int j = 0; j < Q_N; ++j) s += q[((size_t)j * B_N + b) * D_N + tid];
  qsout[b * 256 + tid] = s;
  qsh[tid] = s;
  __syncthreads();
  float z = 0.f;
  for (int n = 0; n < 256; ++n) z += WquT[n * 256 + tid] * qsh[n];
  zbout[b * 256 + tid] = z;
}

// ---------------- prep_K: K_b = Q^T (Q Wqu^T), bf16 2-way split --------------
__global__ void prep_K(const float* __restrict__ q, const float* __restrict__ WquT,
                       unsigned short* __restrict__ KbH, unsigned short* __restrict__ KbM) {
  extern __shared__ float qb[];                 // 128 x 257
  const int b = blockIdx.x >> 2, ic = blockIdx.x & 3, tid = threadIdx.x;
  for (int j = 0; j < Q_N; ++j)
    qb[j * 257 + tid] = q[((size_t)j * B_N + b) * D_N + tid];
  __syncthreads();
  float Kacc[64];
#pragma unroll
  for (int i = 0; i < 64; ++i) Kacc[i] = 0.f;
  const int i0 = ic * 64;
  for (int qc = 0; qc < 16; ++qc) {
    float Pq[8];
#pragma unroll
    for (int qq = 0; qq < 8; ++qq) Pq[qq] = 0.f;
    for (int n = 0; n < 256; ++n) {
      float wv = WquT[n * 256 + tid];
#pragma unroll
      for (int qq = 0; qq < 8; ++qq) Pq[qq] += qb[(qc * 8 + qq) * 257 + n] * wv;
    }
#pragma unroll
    for (int i = 0; i < 64; ++i) {
      float a = 0.f;
#pragma unroll
      for (int qq = 0; qq < 8; ++qq) a += qb[(qc * 8 + qq) * 257 + i0 + i] * Pq[qq];
      Kacc[i] += a;
    }
  }
#pragma unroll
  for (int i = 0; i < 64; ++i) {
    float x = Kacc[i];
    unsigned hb = __float_as_uint(x) & 0xffff0000u;
    float r1 = x - __uint_as_float(hb);
    size_t o = ((size_t)b * 256 + i0 + i) * 256 + tid;
    KbH[o] = (unsigned short)(hb >> 16);
    KbM[o] = (unsigned short)((__float_as_uint(r1) & 0xffff0000u) >> 16);
  }
}

// ---------------- group sync: 16 per-WG flags (private 64B lines) -----------
// Busy poll with 16 lanes; lanes >=16 hold v=val so __any terminates.
__device__ __forceinline__ void wait_flags16(const unsigned* f, unsigned val) {
  const int l = threadIdx.x & 63;
  const unsigned* fp = f + (l & 15) * 16;
  unsigned v = val;
  if (l < 16)
    v = __hip_atomic_load(fp, __ATOMIC_RELAXED, __HIP_MEMORY_SCOPE_AGENT);
  while (__any((int)(v < val))) {
    if (l < 16)
      v = __hip_atomic_load(fp, __ATOMIC_RELAXED, __HIP_MEMORY_SCOPE_AGENT);
  }
}

// ---------------- main: 16 groups x 4 batches, 256 WGs (full chip) -----------
// One-hop sync; gate/md stores are line-exclusive per wave; partial-beta in a
// separate region with 32B wave-private slots (2-way line sharing max).
// Hierarchical signal: wave drains own stores -> LDS count; the WG's last
// wave stores the per-WG flag (16 private flag lines per group, no barrier).
__launch_bounds__(NT, 1)
__global__ void pq_main(const float* __restrict__ p,
                        const float* __restrict__ bih, const float* __restrict__ bhh,
                        const unsigned short* __restrict__ Wh,
                        const unsigned short* __restrict__ Wm,
                        const unsigned short* __restrict__ KbH,
                        const unsigned short* __restrict__ KbM,
                        const float* __restrict__ qs, const float* __restrict__ zb,
                        const float* __restrict__ v0,
                        float* G0, float* G1, float* Gp0, float* Gp1,
                        unsigned* flags, float* __restrict__ out) {
  __shared__ __align__(16) float vsh[GB * VP];     // v_t f32
  __shared__ __align__(16) short vshH[GB * VPS];   // v_t split planes (MFMA A)
  __shared__ __align__(16) short vshM[GB * VPS];
  __shared__ __align__(16) short vshL[GB * VPS];
  __shared__ float bL[1024];
  __shared__ float qsL[GB * 256];
  __shared__ float zL[GB * 256];
  __shared__ unsigned wgc;                         // per-WG drain counter

  const int tid  = threadIdx.x;
  const int bid  = blockIdx.x;
  const int g    = bid & 15;
  const int m    = bid >> 4;
  const int lane = tid & 63;
  const int widx = tid >> 6;
  const int gw   = m * 4 + widx;          // 0..63 group-wave
  const int n2   = 512  + gw * 16;        // gi cols
  const int n3   = 1536 + gw * 16;        // gh cols
  const int bmd  = gw >> 4;               // md batch-in-group 0..3
  const int ct   = gw & 15;               // md col-tile 0..15
  const int pt   = gw & 31;               // pupv col-tile 0..31
  const int kh   = gw >> 5;               // pupv k-half 0/1
  const int n1   = pt * 16;
  const int row  = lane & 15;
  const int arow = lane & 3;              // A-row: batches 0..3 (4x dup)
  const int kb   = lane >> 4;
  const int r0q  = lane >> 4;

  unsigned* flagsG = flags + g * 256;     // 16 WG-flags, 64B apart

  const int nb = lane * 4;                // phase-2: 4 elems per lane
  const int bi = widx;                    // phase-2: wave = batch row

  if (tid == 0) wgc = 0u;
  // constants + v0 -> LDS (v0 also pre-split into planes)
  for (int i = tid; i < 1024; i += NT) bL[i] = bih[i] + bhh[i];
  for (int i = tid; i < GB * 256; i += NT) {
    int r = i >> 8, c = i & 255;
    qsL[i] = qs[(size_t)(g * GB + r) * 256 + c];
    zL[i]  = zb[(size_t)(g * GB + r) * 256 + c];
    float vv = v0[(size_t)(g * GB + r) * 256 + c];
    vsh[r * VP + c] = vv;
    unsigned uh = __float_as_uint(vv) & 0xffff0000u;
    float r1 = vv - __uint_as_float(uh);
    unsigned um = __float_as_uint(r1) & 0xffff0000u;
    float s = r1 - __uint_as_float(um);
    vshH[r * VPS + c] = (short)(uh >> 16);
    vshM[r * VPS + c] = (short)(um >> 16);
    vshL[r * VPS + c] = (short)(__float_as_uint(s) >> 16);
  }
  __syncthreads();

  // register-resident B fragments: gi, gh, 1x md(K), 0.5x pu/pv
  short8 Bhg[8], Bmg[8], Bh2[8], Bm2[8], Kh[8], Km[8], Bh1[4], Bm1[4];
#pragma unroll
  for (int ks = 0; ks < 8; ++ks) {
    int ko = ks * 32 + kb * 8;
    int c2 = (n2 + row) * 256 + ko;
    int c3 = (n3 + row) * 256 + ko;
    Bhg[ks] = *(const short8*)&Wh[c2];  Bmg[ks] = *(const short8*)&Wm[c2];
    Bh2[ks] = *(const short8*)&Wh[c3];  Bm2[ks] = *(const short8*)&Wm[c3];
    size_t k0 = ((size_t)(g * GB + bmd) * 256 + ct * 16 + row) * 256 + ko;
    Kh[ks] = *(const short8*)&KbH[k0];  Km[ks] = *(const short8*)&KbM[k0];
  }
#pragma unroll
  for (int ks = 0; ks < 4; ++ks) {
    int kop = (kh * 4 + ks) * 32 + kb * 8;
    int c1 = (n1 + row) * 256 + kop;
    Bh1[ks] = *(const short8*)&Wh[c1];  Bm1[ks] = *(const short8*)&Wm[c1];
  }

  // gh tile for t=0 + ut prefetch for t=0
  floatx4 acc2 = {0.f, 0.f, 0.f, 0.f};
  float wut[4] = {0.f, 0.f, 0.f, 0.f};
  {
    const float* pb = p + ((size_t)0 * B_N + g * GB) * D_N;
#pragma unroll
    for (int ks = 0; ks < 8; ++ks) {
      float xa[8];
      const float* pr = pb + arow * D_N + ks * 32 + kb * 8;
      *(float4*)&xa[0] = *(const float4*)pr;
      *(float4*)&xa[4] = *(const float4*)(pr + 4);
      Split3 A = split8(xa);
      acc2 = mfma5(acc2, A, Bh2[ks], Bm2[ks]);
    }
    if (n1 < 256 && lane < 16) {
#pragma unroll
      for (int r = 0; r < 4; ++r)
        wut[r] = p[((size_t)0 * B_N + g * GB + r) * D_N + n1 + lane];
    }
  }

  for (int t = 0; t < T_LEN; ++t) {
    float* Gc  = (t & 1) ? G1 : G0;
    float* Gpc = (t & 1) ? Gp1 : Gp0;

    // ---- phase 1: A-fragments from the pre-split planes; ~2.5 chains ----
    floatx4 accg = {0.f,0.f,0.f,0.f}, mdac = {0.f,0.f,0.f,0.f}, ac1 = {0.f,0.f,0.f,0.f};
#pragma unroll
    for (int ks = 0; ks < 8; ++ks) {
      int co = ks * 32 + kb * 8;
      Split3 A;
      A.h = *(const short8*)&vshH[arow * VPS + co];
      A.m = *(const short8*)&vshM[arow * VPS + co];
      A.l = *(const short8*)&vshL[arow * VPS + co];
      accg = mfma5(accg, A, Bhg[ks], Bmg[ks]);
      mdac = mfma5(mdac, A, Kh[ks], Km[ks]);
      if ((ks >> 2) == kh) ac1 = mfma5(ac1, A, Bh1[ks & 3], Bm1[ks & 3]);
    }

    // gates: DIRECT per-wave stores (line-exclusive: cols gw*16.. per row)
    if (r0q == 0) {
#pragma unroll
      for (int r = 0; r < 4; ++r)
        st1_sc(&Gc[(size_t)(g * GB + r) * GROW + gw * 16 + row],
               accg[r] + acc2[r]);
    }
    // md: row bmd only is valid; tile = one exclusive 64B line
    {
      float mdv = (bmd == 0) ? mdac[0] : (bmd == 1) ? mdac[1]
                : (bmd == 2) ? mdac[2] : mdac[3];
      if (r0q == 0)
        st1_sc(&Gc[(size_t)(g * GB + bmd) * GROW + 1024 + ct * 16 + row], mdv);
    }
    // pu/pv: partial beta -> wave-private 32B slot in Gp (2-way line share)
    {
      float pr4[4];
#pragma unroll
      for (int r = 0; r < 4; ++r) {
        pr4[r] = 0.f;
        if (r0q == 0) {
          float w = (n1 < 256) ? wut[r] : vsh[r * VP + (n1 - 256) + row];
          pr4[r] = ac1[r] * w;
        }
      }
#pragma unroll
      for (int off = 1; off < 16; off <<= 1) {
#pragma unroll
        for (int r = 0; r < 4; ++r) pr4[r] += __shfl_xor(pr4[r], off);
      }
      if (lane == 0) {
#pragma unroll
        for (int r = 0; r < 4; ++r)
          st1_sc(&Gpc[g * 512 + gw * 8 + r], pr4[r]);
      }
    }
    // drain OWN stores; LDS count; WG's LAST wave stores the per-WG flag
    vm_drain();
    if (lane == 0) {
      unsigned old = atomicAdd(&wgc, 1u);
      if (old == (unsigned)(4 * t + 3))
        __hip_atomic_store(flagsG + m * 16, (unsigned)(t + 1),
                           __ATOMIC_RELAXED, __HIP_MEMORY_SCOPE_AGENT);
    }

    // ---- gh + ut prefetch for t+1 (hides in the wait window) ----
    floatx4 acc2n = {0.f,0.f,0.f,0.f};
    float wutn[4] = {0.f, 0.f, 0.f, 0.f};
    if (t + 1 < T_LEN) {
      const float* pb = p + ((size_t)(t + 1) * B_N + g * GB) * D_N;
#pragma unroll
      for (int ks = 0; ks < 8; ++ks) {
        float xa[8];
        const float* pr = pb + arow * D_N + ks * 32 + kb * 8;
        *(float4*)&xa[0] = *(const float4*)pr;
        *(float4*)&xa[4] = *(const float4*)(pr + 4);
        Split3 A = split8(xa);
        acc2n = mfma5(acc2n, A, Bh2[ks], Bm2[ks]);
      }
      if (n1 < 256 && lane < 16) {
#pragma unroll
        for (int r = 0; r < 4; ++r)
          wutn[r] = p[((size_t)(t + 1) * B_N + g * GB + r) * D_N + n1 + lane];
      }
    }

    // ---- the single hop: busy-poll 16 per-WG flags ----
    wait_flags16(flagsG, (unsigned)(t + 1));

    // ---- redundant local phase 2: wave widx owns batch row widx ----
    const float* gr = Gc + (size_t)(g * GB + bi) * GROW;
    floatx4 G0v = ld4_sc(gr + nb);
    floatx4 G1v = ld4_sc(gr + 256 + nb);
    floatx4 G2v = ld4_sc(gr + 512 + nb);
    floatx4 G3v = ld4_sc(gr + 768 + nb);
    floatx4 M4  = ld4_sc(gr + 1024 + nb);
    float part  = ld1_sc(&Gpc[g * 512 + lane * 8 + bi]);
    vm_drain();
    TIE(G0v); TIE(G1v); TIE(G2v); TIE(G3v); TIE(M4); TIE(part);

    floatx4 v4 = *(const floatx4*)&vsh[bi * VP + nb];
    float rz = 0.f;
#pragma unroll
    for (int e = 0; e < 4; ++e) rz += zL[bi * 256 + nb + e] * v4[e];
    float sx = part, sy = rz;
#pragma unroll
    for (int off = 1; off < 64; off <<= 1) {
      sx += __shfl_xor(sx, off);
      sy += __shfl_xor(sy, off);
    }
    float beta = sx;
    float invr = 1.f / (sy + 128.f * beta);   // r = v.z + Q*beta

    float h4[4];
#pragma unroll
    for (int e = 0; e < 4; ++e) {
      int n = nb + e;
      float cctx = (M4[e] + beta * qsL[bi * 256 + n]) * invr;
      float cn = fsigmoid(G1v[e] + bL[256 + n]) * cctx
               + fsigmoid(G0v[e] + bL[n]) * ftanh(G2v[e] + bL[512 + n]);
      h4[e] = fsigmoid(G3v[e] + bL[768 + n]) * ftanh(cn);
    }
    *(floatx4*)&vsh[bi * VP + nb] = *(const floatx4*)&h4[0];
    {
      union { unsigned u[2]; short s[4]; } PH, PM, PL;
#pragma unroll
      for (int e = 0; e < 4; ++e) {
        unsigned uh = __float_as_uint(h4[e]) & 0xffff0000u;
        float r1 = h4[e] - __uint_as_float(uh);
        unsigned um = __float_as_uint(r1) & 0xffff0000u;
        float s = r1 - __uint_as_float(um);
        PH.s[e] = (short)(uh >> 16);
        PM.s[e] = (short)(um >> 16);
        PL.s[e] = (short)(__float_as_uint(s) >> 16);
      }
      *(unsigned*)&vshH[bi * VPS + nb]     = PH.u[0];
      *(unsigned*)&vshH[bi * VPS + nb + 2] = PH.u[1];
      *(unsigned*)&vshM[bi * VPS + nb]     = PM.u[0];
      *(unsigned*)&vshM[bi * VPS + nb + 2] = PM.u[1];
      *(unsigned*)&vshL[bi * VPS + nb]     = PL.u[0];
      *(unsigned*)&vshL[bi * VPS + nb + 2] = PL.u[1];
    }
    __syncthreads();
    acc2 = acc2n;
#pragma unroll
    for (int r = 0; r < 4; ++r) wut[r] = wutn[r];
  }

  if (m < GB) out[(size_t)(g * GB + m) * 256 + tid] = vsh[m * VP + tid];
}

extern "C" void kernel_launch(void* const* d_in, const int* in_sizes, int n_in,
                              void* d_out, int out_size, void* d_ws, size_t ws_size,
                              hipStream_t stream) {
  const float* p   = (const float*)d_in[0];
  const float* q   = (const float*)d_in[1];
  const float* v0  = (const float*)d_in[2];
  const float* Wpu = (const float*)d_in[3];
  const float* Wqu = (const float*)d_in[4];
  const float* Wpv = (const float*)d_in[5];
  const float* Wih = (const float*)d_in[6];
  const float* Whh = (const float*)d_in[7];
  const float* bih = (const float*)d_in[8];
  const float* bhh = (const float*)d_in[9];
  float* out = (float*)d_out;

  char* ws = (char*)d_ws;
  unsigned short* Wh  = (unsigned short*)(ws + 0x000000);  // 1,310,720 B
  unsigned short* Wm  = (unsigned short*)(ws + 0x140000);  // 1,310,720 B
  float*    G0     = (float*)(ws + 0x280000);              //   327,680 B (GROW=1280)
  float*    G1     = (float*)(ws + 0x2D0000);              //   327,680 B
  float*    WquT   = (float*)(ws + 0x2D0000);              // alias G1 (prep-only)
  float*    Gp0    = (float*)(ws + 0x320000);              //    32,768 B (partials)
  float*    Gp1    = (float*)(ws + 0x328000);              //    32,768 B
  unsigned* flags  = (unsigned*)(ws + 0x330000);           //    16,384 B
  float*    qs     = (float*)(ws + 0x334000);              //    65,536 B
  float*    zbv    = (float*)(ws + 0x344000);              //    65,536 B
  unsigned short* KbH = (unsigned short*)(ws + 0x354000);  // 8,388,608 B
  unsigned short* KbM = (unsigned short*)(ws + 0xB54000);  // 8,388,608 B
  if (ws_size < 0x1360000u) return;                        // used: 0x1354000

  const int prep_items = WCOLS * 256 + 65536 + 4096;       // 725,952
  prep_kernel<<<(prep_items + 255) / 256, 256, 0, stream>>>(
      Wpu, Wqu, Wpv, Wih, Whh, Wh, Wm, WquT, flags);

  prep_qz<<<64, 256, 0, stream>>>(q, WquT, qs, zbv);

  const size_t k_smem = 128 * 257 * sizeof(float);          // 131,584 B
  hipFuncSetAttribute(reinterpret_cast<const void*>(prep_K),
                      hipFuncAttributeMaxDynamicSharedMemorySize, (int)k_smem);
  prep_K<<<256, 256, k_smem, stream>>>(q, WquT, KbH, KbM);

  // 256 WGs = 16 groups x 16 members (256 threads each) — full chip.
  pq_main<<<NGRP * GWGS, NT, 0, stream>>>(p, bih, bhh, Wh, Wm, KbH, KbM, qs, zbv,
                                          v0, G0, G1, Gp0, Gp1, flags, out);
}

// Round 20
// 7598.466 us; speedup vs baseline: 1.0378x; 1.0378x over previous
//
#include <hip/hip_runtime.h>

#define T_LEN 1024
#define B_N   64
#define D_N   256
#define Q_N   128
#define WCOLS 2560      // weights: 256 pu | 256 pv | 1024 gi | 1024 gh
#define GROW  1344      // G row: 1024 gates | 256 md | 64 beta-partials
#define NT    256
#define NGRP  16        // 16 groups x 4 batches -> 256 WGs, full chip
#define GB    4
#define GWGS  16
#define FSTRIDE 32      // counter per 128B line
#define VP    260       // vsh f32 row pitch
#define VPS   264       // bf16 plane row pitch (shorts)

typedef __attribute__((ext_vector_type(8))) short short8;
typedef __attribute__((ext_vector_type(4))) float floatx4;

#define MFMA16(A, B, C) __builtin_amdgcn_mfma_f32_16x16x32_bf16((A), (B), (C), 0, 0, 0)

__device__ __forceinline__ float fsigmoid(float x) { return 1.f / (1.f + __expf(-x)); }
__device__ __forceinline__ float ftanh(float x) {
  float ax = fabsf(x);
  float e = __expf(-2.f * ax);
  float r = (1.f - e) / (1.f + e);
  return (x < 0.f) ? -r : r;
}

// ---- PROVEN exchange primitives -------------------------------------------
__device__ __forceinline__ floatx4 ld4_sc(const float* a) {
  floatx4 r;
  asm volatile("global_load_dwordx4 %0, %1, off sc0 sc1" : "=v"(r) : "v"(a) : "memory");
  return r;
}
__device__ __forceinline__ float ld1_sc(const float* a) {
  float r;
  asm volatile("global_load_dword %0, %1, off sc0 sc1" : "=v"(r) : "v"(a) : "memory");
  return r;
}
__device__ __forceinline__ void st1_sc(float* a, float v) {
  asm volatile("global_store_dword %0, %1, off sc0 sc1" :: "v"(a), "v"(v) : "memory");
}
__device__ __forceinline__ void vm_drain() { asm volatile("s_waitcnt vmcnt(0)" ::: "memory"); }
#define TIE(x) asm volatile("" : "+v"(x))

// 3-term truncation split of A (p staging only; v is pre-split in LDS)
struct Split3 { short8 h, m, l; };
__device__ __forceinline__ Split3 split8(const float* x) {
  union U { unsigned u[4]; short8 s; } H, M, L;
#pragma unroll
  for (int i = 0; i < 4; ++i) {
    float x0 = x[2 * i], x1 = x[2 * i + 1];
    unsigned h0 = __float_as_uint(x0) & 0xffff0000u;
    unsigned h1 = __float_as_uint(x1) & 0xffff0000u;
    float r0 = x0 - __uint_as_float(h0);
    float r1 = x1 - __uint_as_float(h1);
    unsigned m0 = __float_as_uint(r0) & 0xffff0000u;
    unsigned m1 = __float_as_uint(r1) & 0xffff0000u;
    float s0 = r0 - __uint_as_float(m0);
    float s1 = r1 - __uint_as_float(m1);
    H.u[i] = (h0 >> 16) | h1;
    M.u[i] = (m0 >> 16) | m1;
    L.u[i] = (__float_as_uint(s0) >> 16) | (__float_as_uint(s1) & 0xffff0000u);
  }
  Split3 r; r.h = H.s; r.m = M.s; r.l = L.s; return r;
}

__device__ __forceinline__ floatx4 mfma5(floatx4 acc, const Split3& A, short8 Bh, short8 Bm) {
  acc = MFMA16(A.l, Bh, acc);
  acc = MFMA16(A.m, Bm, acc);
  acc = MFMA16(A.m, Bh, acc);
  acc = MFMA16(A.h, Bm, acc);
  acc = MFMA16(A.h, Bh, acc);
  return acc;
}

// ---------------- prep: W -> bf16 2-way split; WquT; flags=0 -----------------
__global__ void prep_kernel(const float* __restrict__ Wpu, const float* __restrict__ Wqu,
                            const float* __restrict__ Wpv, const float* __restrict__ Wih,
                            const float* __restrict__ Whh,
                            unsigned short* __restrict__ Wh, unsigned short* __restrict__ Wm,
                            float* __restrict__ WquT, unsigned* __restrict__ flags) {
  int idx = blockIdx.x * 256 + threadIdx.x;
  const int total = WCOLS * 256;                // 655360
  if (idx < total) {
    int n = idx >> 8, k = idx & 255;
    float w;
    if      (n < 256)  w = Wpu[k * 256 + n];            // pu
    else if (n < 512)  w = Wpv[k * 256 + (n - 256)];    // pv
    else if (n < 1536) w = Wih[(n - 512) * 256 + k];    // gi
    else               w = Whh[(n - 1536) * 256 + k];   // gh
    unsigned hb = __float_as_uint(w) & 0xffff0000u;
    float r1 = w - __uint_as_float(hb);
    Wh[idx] = (unsigned short)(hb >> 16);
    Wm[idx] = (unsigned short)((__float_as_uint(r1) & 0xffff0000u) >> 16);
  } else if (idx < total + 65536) {
    int i = idx - total, n = i >> 8, k = i & 255;
    WquT[n * 256 + k] = Wqu[k * 256 + n];
  } else if (idx < total + 65536 + 8192) {
    flags[idx - total - 65536] = 0u;
  }
}

// ---------------- prep_qz: qs_b = sum_j q_j ; z_b = Wqu @ qs_b ---------------
__global__ void prep_qz(const float* __restrict__ q, const float* __restrict__ WquT,
                        float* __restrict__ qsout, float* __restrict__ zbout) {
  __shared__ float qsh[256];
  const int b = blockIdx.x, tid = threadIdx.x;
  float s = 0.f;
  for (int j = 0; j < Q_N; ++j) s += q[((size_t)j * B_N + b) * D_N + tid];
  qsout[b * 256 + tid] = s;
  qsh[tid] = s;
  __syncthreads();
  float z = 0.f;
  for (int n = 0; n < 256; ++n) z += WquT[n * 256 + tid] * qsh[n];
  zbout[b * 256 + tid] = z;
}

// ---------------- prep_K: K_b = Q^T (Q Wqu^T), bf16 2-way split --------------
__global__ void prep_K(const float* __restrict__ q, const float* __restrict__ WquT,
                       unsigned short* __restrict__ KbH, unsigned short* __restrict__ KbM) {
  extern __shared__ float qb[];                 // 128 x 257
  const int b = blockIdx.x >> 2, ic = blockIdx.x & 3, tid = threadIdx.x;
  for (int j = 0; j < Q_N; ++j)
    qb[j * 257 + tid] = q[((size_t)j * B_N + b) * D_N + tid];
  __syncthreads();
  float Kacc[64];
#pragma unroll
  for (int i = 0; i < 64; ++i) Kacc[i] = 0.f;
  const int i0 = ic * 64;
  for (int qc = 0; qc < 16; ++qc) {
    float Pq[8];
#pragma unroll
    for (int qq = 0; qq < 8; ++qq) Pq[qq] = 0.f;
    for (int n = 0; n < 256; ++n) {
      float wv = WquT[n * 256 + tid];
#pragma unroll
      for (int qq = 0; qq < 8; ++qq) Pq[qq] += qb[(qc * 8 + qq) * 257 + n] * wv;
    }
#pragma unroll
    for (int i = 0; i < 64; ++i) {
      float a = 0.f;
#pragma unroll
      for (int qq = 0; qq < 8; ++qq) a += qb[(qc * 8 + qq) * 257 + i0 + i] * Pq[qq];
      Kacc[i] += a;
    }
  }
#pragma unroll
  for (int i = 0; i < 64; ++i) {
    float x = Kacc[i];
    unsigned hb = __float_as_uint(x) & 0xffff0000u;
    float r1 = x - __uint_as_float(hb);
    size_t o = ((size_t)b * 256 + i0 + i) * 256 + tid;
    KbH[o] = (unsigned short)(hb >> 16);
    KbM[o] = (unsigned short)((__float_as_uint(r1) & 0xffff0000u) >> 16);
  }
}

// ---------------- group sync: ONE counter per group, per-WAVE signaling ------
__device__ __forceinline__ void wait_counter(const unsigned* c, unsigned target) {
  unsigned v = __hip_atomic_load(c, __ATOMIC_RELAXED, __HIP_MEMORY_SCOPE_AGENT);
  while (v < target)
    v = __hip_atomic_load(c, __ATOMIC_RELAXED, __HIP_MEMORY_SCOPE_AGENT);
}

// ---------------- main: 16 groups x 4 batches, 256 WGs (full chip) -----------
// Per group (64 waves): gi = 1 chain/wave; md = 1 chain/wave; pu/pv =
// half-chain/wave. One-hop sync via per-wave counter signaling; gate slices
// stored DIRECTLY per-wave (no LDS staging, no pre-signal barrier) — one
// barrier per step. ut for partial-beta prefetched a step ahead.
__launch_bounds__(NT, 1)
__global__ void pq_main(const float* __restrict__ p,
                        const float* __restrict__ bih, const float* __restrict__ bhh,
                        const unsigned short* __restrict__ Wh,
                        const unsigned short* __restrict__ Wm,
                        const unsigned short* __restrict__ KbH,
                        const unsigned short* __restrict__ KbM,
                        const float* __restrict__ qs, const float* __restrict__ zb,
                        const float* __restrict__ v0,
                        float* G0, float* G1, unsigned* flags,
                        float* __restrict__ out) {
  __shared__ __align__(16) float vsh[GB * VP];     // v_t f32
  __shared__ __align__(16) short vshH[GB * VPS];   // v_t split planes (MFMA A)
  __shared__ __align__(16) short vshM[GB * VPS];
  __shared__ __align__(16) short vshL[GB * VPS];
  __shared__ float bL[1024];
  __shared__ float qsL[GB * 256];
  __shared__ float zL[GB * 256];

  const int tid  = threadIdx.x;
  const int bid  = blockIdx.x;
  const int g    = bid & 15;
  const int m    = bid >> 4;
  const int lane = tid & 63;
  const int widx = tid >> 6;
  const int gw   = m * 4 + widx;          // 0..63 group-wave
  const int n2   = 512  + gw * 16;        // gi cols
  const int n3   = 1536 + gw * 16;        // gh cols
  const int bmd  = gw >> 4;               // md batch-in-group 0..3
  const int ct   = gw & 15;               // md col-tile 0..15
  const int pt   = gw & 31;               // pupv col-tile 0..31
  const int kh   = gw >> 5;               // pupv k-half 0/1
  const int n1   = pt * 16;
  const int row  = lane & 15;
  const int arow = lane & 3;              // A-row: batches 0..3 (4x dup)
  const int kb   = lane >> 4;
  const int r0q  = lane >> 4;

  unsigned* cnt = flags + g * FSTRIDE;    // one counter per group (128B line)

  const int nb = lane * 4;                // phase-2: 4 elems per lane
  const int bi = widx;                    // phase-2: wave = batch row

  // constants + v0 -> LDS (v0 also pre-split into planes)
  for (int i = tid; i < 1024; i += NT) bL[i] = bih[i] + bhh[i];
  for (int i = tid; i < GB * 256; i += NT) {
    int r = i >> 8, c = i & 255;
    qsL[i] = qs[(size_t)(g * GB + r) * 256 + c];
    zL[i]  = zb[(size_t)(g * GB + r) * 256 + c];
    float vv = v0[(size_t)(g * GB + r) * 256 + c];
    vsh[r * VP + c] = vv;
    unsigned uh = __float_as_uint(vv) & 0xffff0000u;
    float r1 = vv - __uint_as_float(uh);
    unsigned um = __float_as_uint(r1) & 0xffff0000u;
    float s = r1 - __uint_as_float(um);
    vshH[r * VPS + c] = (short)(uh >> 16);
    vshM[r * VPS + c] = (short)(um >> 16);
    vshL[r * VPS + c] = (short)(__float_as_uint(s) >> 16);
  }
  __syncthreads();

  // register-resident B fragments: gi, gh, 1x md(K), 0.5x pu/pv
  short8 Bhg[8], Bmg[8], Bh2[8], Bm2[8], Kh[8], Km[8], Bh1[4], Bm1[4];
#pragma unroll
  for (int ks = 0; ks < 8; ++ks) {
    int ko = ks * 32 + kb * 8;
    int c2 = (n2 + row) * 256 + ko;
    int c3 = (n3 + row) * 256 + ko;
    Bhg[ks] = *(const short8*)&Wh[c2];  Bmg[ks] = *(const short8*)&Wm[c2];
    Bh2[ks] = *(const short8*)&Wh[c3];  Bm2[ks] = *(const short8*)&Wm[c3];
    size_t k0 = ((size_t)(g * GB + bmd) * 256 + ct * 16 + row) * 256 + ko;
    Kh[ks] = *(const short8*)&KbH[k0];  Km[ks] = *(const short8*)&KbM[k0];
  }
#pragma unroll
  for (int ks = 0; ks < 4; ++ks) {
    int kop = (kh * 4 + ks) * 32 + kb * 8;
    int c1 = (n1 + row) * 256 + kop;
    Bh1[ks] = *(const short8*)&Wh[c1];  Bm1[ks] = *(const short8*)&Wm[c1];
  }

  // gh tile for t=0 + ut prefetch for t=0
  floatx4 acc2 = {0.f, 0.f, 0.f, 0.f};
  float wut[4] = {0.f, 0.f, 0.f, 0.f};
  {
    const float* pb = p + ((size_t)0 * B_N + g * GB) * D_N;
#pragma unroll
    for (int ks = 0; ks < 8; ++ks) {
      float xa[8];
      const float* pr = pb + arow * D_N + ks * 32 + kb * 8;
      *(float4*)&xa[0] = *(const float4*)pr;
      *(float4*)&xa[4] = *(const float4*)(pr + 4);
      Split3 A = split8(xa);
      acc2 = mfma5(acc2, A, Bh2[ks], Bm2[ks]);
    }
    if (n1 < 256 && lane < 16) {
#pragma unroll
      for (int r = 0; r < 4; ++r)
        wut[r] = p[((size_t)0 * B_N + g * GB + r) * D_N + n1 + lane];
    }
  }

  for (int t = 0; t < T_LEN; ++t) {
    float* Gc = (t & 1) ? G1 : G0;

    // ---- phase 1: A-fragments from the pre-split planes; ~2.5 chains ----
    floatx4 accg = {0.f,0.f,0.f,0.f}, mdac = {0.f,0.f,0.f,0.f}, ac1 = {0.f,0.f,0.f,0.f};
#pragma unroll
    for (int ks = 0; ks < 8; ++ks) {
      int co = ks * 32 + kb * 8;
      Split3 A;
      A.h = *(const short8*)&vshH[arow * VPS + co];
      A.m = *(const short8*)&vshM[arow * VPS + co];
      A.l = *(const short8*)&vshL[arow * VPS + co];
      accg = mfma5(accg, A, Bhg[ks], Bmg[ks]);
      mdac = mfma5(mdac, A, Kh[ks], Km[ks]);
      if ((ks >> 2) == kh) ac1 = mfma5(ac1, A, Bh1[ks & 3], Bm1[ks & 3]);
    }

    // gates: DIRECT per-wave stores (rows 0..3 valid; cols gw*16+row)
    if (r0q == 0) {
#pragma unroll
      for (int r = 0; r < 4; ++r)
        st1_sc(&Gc[(size_t)(g * GB + r) * GROW + gw * 16 + row],
               accg[r] + acc2[r]);
    }
    // md: row bmd only is valid (K is batch-specific); 64B-contiguous store
    {
      float mdv = (bmd == 0) ? mdac[0] : (bmd == 1) ? mdac[1]
                : (bmd == 2) ? mdac[2] : mdac[3];
      if (r0q == 0)
        st1_sc(&Gc[(size_t)(g * GB + bmd) * GROW + 1024 + ct * 16 + row], mdv);
    }
    // pu/pv: producer-side partial beta (k-half partials add linearly)
    {
      float pr4[4];
#pragma unroll
      for (int r = 0; r < 4; ++r) {
        pr4[r] = 0.f;
        if (r0q == 0) {
          float w = (n1 < 256) ? wut[r] : vsh[r * VP + (n1 - 256) + row];
          pr4[r] = ac1[r] * w;
        }
      }
#pragma unroll
      for (int off = 1; off < 16; off <<= 1) {
#pragma unroll
        for (int r = 0; r < 4; ++r) pr4[r] += __shfl_xor(pr4[r], off);
      }
      if (lane == 0) {
#pragma unroll
        for (int r = 0; r < 4; ++r)
          st1_sc(&Gc[(size_t)(g * GB + r) * GROW + 1280 + gw], pr4[r]);
      }
    }
    // this wave's exchange stores all issued: drain OWN stores, signal
    vm_drain();
    if (lane == 0)
      __hip_atomic_fetch_add(cnt, 1u, __ATOMIC_RELAXED, __HIP_MEMORY_SCOPE_AGENT);

    // ---- gh + ut prefetch for t+1 (hides in the wait window) ----
    floatx4 acc2n = {0.f,0.f,0.f,0.f};
    float wutn[4] = {0.f, 0.f, 0.f, 0.f};
    if (t + 1 < T_LEN) {
      const float* pb = p + ((size_t)(t + 1) * B_N + g * GB) * D_N;
#pragma unroll
      for (int ks = 0; ks < 8; ++ks) {
        float xa[8];
        const float* pr = pb + arow * D_N + ks * 32 + kb * 8;
        *(float4*)&xa[0] = *(const float4*)pr;
        *(float4*)&xa[4] = *(const float4*)(pr + 4);
        Split3 A = split8(xa);
        acc2n = mfma5(acc2n, A, Bh2[ks], Bm2[ks]);
      }
      if (n1 < 256 && lane < 16) {
#pragma unroll
        for (int r = 0; r < 4; ++r)
          wutn[r] = p[((size_t)(t + 1) * B_N + g * GB + r) * D_N + n1 + lane];
      }
    }

    // ---- the single hop: busy-poll the aggregated counter ----
    wait_counter(cnt, (unsigned)(64 * (t + 1)));

    // ---- redundant local phase 2: wave widx owns batch row widx ----
    const float* gr = Gc + (size_t)(g * GB + bi) * GROW;
    floatx4 G0v = ld4_sc(gr + nb);
    floatx4 G1v = ld4_sc(gr + 256 + nb);
    floatx4 G2v = ld4_sc(gr + 512 + nb);
    floatx4 G3v = ld4_sc(gr + 768 + nb);
    floatx4 M4  = ld4_sc(gr + 1024 + nb);
    float part  = ld1_sc(gr + 1280 + lane);
    vm_drain();
    TIE(G0v); TIE(G1v); TIE(G2v); TIE(G3v); TIE(M4); TIE(part);

    floatx4 v4 = *(const floatx4*)&vsh[bi * VP + nb];
    float rz = 0.f;
#pragma unroll
    for (int e = 0; e < 4; ++e) rz += zL[bi * 256 + nb + e] * v4[e];
    float sx = part, sy = rz;
#pragma unroll
    for (int off = 1; off < 64; off <<= 1) {
      sx += __shfl_xor(sx, off);
      sy += __shfl_xor(sy, off);
    }
    float beta = sx;
    float invr = 1.f / (sy + 128.f * beta);   // r = v.z + Q*beta

    float h4[4];
#pragma unroll
    for (int e = 0; e < 4; ++e) {
      int n = nb + e;
      float cctx = (M4[e] + beta * qsL[bi * 256 + n]) * invr;
      float cn = fsigmoid(G1v[e] + bL[256 + n]) * cctx
               + fsigmoid(G0v[e] + bL[n]) * ftanh(G2v[e] + bL[512 + n]);
      h4[e] = fsigmoid(G3v[e] + bL[768 + n]) * ftanh(cn);
    }
    *(floatx4*)&vsh[bi * VP + nb] = *(const floatx4*)&h4[0];
    {
      union { unsigned u[2]; short s[4]; } PH, PM, PL;
#pragma unroll
      for (int e = 0; e < 4; ++e) {
        unsigned uh = __float_as_uint(h4[e]) & 0xffff0000u;
        float r1 = h4[e] - __uint_as_float(uh);
        unsigned um = __float_as_uint(r1) & 0xffff0000u;
        float s = r1 - __uint_as_float(um);
        PH.s[e] = (short)(uh >> 16);
        PM.s[e] = (short)(um >> 16);
        PL.s[e] = (short)(__float_as_uint(s) >> 16);
      }
      *(unsigned*)&vshH[bi * VPS + nb]     = PH.u[0];
      *(unsigned*)&vshH[bi * VPS + nb + 2] = PH.u[1];
      *(unsigned*)&vshM[bi * VPS + nb]     = PM.u[0];
      *(unsigned*)&vshM[bi * VPS + nb + 2] = PM.u[1];
      *(unsigned*)&vshL[bi * VPS + nb]     = PL.u[0];
      *(unsigned*)&vshL[bi * VPS + nb + 2] = PL.u[1];
    }
    __syncthreads();
    acc2 = acc2n;
#pragma unroll
    for (int r = 0; r < 4; ++r) wut[r] = wutn[r];
  }

  if (m < GB) out[(size_t)(g * GB + m) * 256 + tid] = vsh[m * VP + tid];
}

extern "C" void kernel_launch(void* const* d_in, const int* in_sizes, int n_in,
                              void* d_out, int out_size, void* d_ws, size_t ws_size,
                              hipStream_t stream) {
  const float* p   = (const float*)d_in[0];
  const float* q   = (const float*)d_in[1];
  const float* v0  = (const float*)d_in[2];
  const float* Wpu = (const float*)d_in[3];
  const float* Wqu = (const float*)d_in[4];
  const float* Wpv = (const float*)d_in[5];
  const float* Wih = (const float*)d_in[6];
  const float* Whh = (const float*)d_in[7];
  const float* bih = (const float*)d_in[8];
  const float* bhh = (const float*)d_in[9];
  float* out = (float*)d_out;

  char* ws = (char*)d_ws;
  unsigned short* Wh  = (unsigned short*)(ws + 0x000000);  // 1,310,720 B
  unsigned short* Wm  = (unsigned short*)(ws + 0x140000);  // 1,310,720 B
  float*    G0     = (float*)(ws + 0x280000);              //   344,064 B
  float*    G1     = (float*)(ws + 0x2D4000);              //   344,064 B
  float*    WquT   = (float*)(ws + 0x2D4000);              // alias G1 (prep-only)
  unsigned* flags  = (unsigned*)(ws + 0x328000);           //    32,768 B
  float*    qs     = (float*)(ws + 0x330000);              //    65,536 B
  float*    zbv    = (float*)(ws + 0x340000);              //    65,536 B
  unsigned short* KbH = (unsigned short*)(ws + 0x350000);  // 8,388,608 B
  unsigned short* KbM = (unsigned short*)(ws + 0xB50000);  // 8,388,608 B
  if (ws_size < 0x1360000u) return;                        // used: 0x1350000

  const int prep_items = WCOLS * 256 + 65536 + 8192;       // 729,088
  prep_kernel<<<(prep_items + 255) / 256, 256, 0, stream>>>(
      Wpu, Wqu, Wpv, Wih, Whh, Wh, Wm, WquT, flags);

  prep_qz<<<64, 256, 0, stream>>>(q, WquT, qs, zbv);

  const size_t k_smem = 128 * 257 * sizeof(float);          // 131,584 B
  hipFuncSetAttribute(reinterpret_cast<const void*>(prep_K),
                      hipFuncAttributeMaxDynamicSharedMemorySize, (int)k_smem);
  prep_K<<<256, 256, k_smem, stream>>>(q, WquT, KbH, KbM);

  // 256 WGs = 16 groups x 16 members (256 threads each) — full chip.
  pq_main<<<NGRP * GWGS, NT, 0, stream>>>(p, bih, bhh, Wh, Wm, KbH, KbM, qs, zbv,
                                          v0, G0, G1, flags, out);
}